// Round 12
// baseline (187.021 us; speedup 1.0000x reference)
//
#include <hip/hip_runtime.h>
#include <stdint.h>
#include <math.h>

#define FDIM 126
#define TPB 256

// numpy pairwise_sum for n=126 (n <= PW_BLOCKSIZE=128 branch), bit-exact trees.
// Loops unrolled so a(i) is always called with a compile-time constant.
template <typename F>
__device__ __forceinline__ double pw126d(F a) {
    #pragma clang fp contract(off)
    double r0=a(0), r1=a(1), r2=a(2), r3=a(3), r4=a(4), r5=a(5), r6=a(6), r7=a(7);
    #pragma unroll
    for (int i = 8; i < 120; i += 8) {
        r0 += a(i);   r1 += a(i+1); r2 += a(i+2); r3 += a(i+3);
        r4 += a(i+4); r5 += a(i+5); r6 += a(i+6); r7 += a(i+7);
    }
    double res = ((r0 + r1) + (r2 + r3)) + ((r4 + r5) + (r6 + r7));
    res += a(120); res += a(121); res += a(122); res += a(123); res += a(124); res += a(125);
    return res;
}
template <typename F>
__device__ __forceinline__ float pw126f(F a) {
    #pragma clang fp contract(off)
    float r0=a(0), r1=a(1), r2=a(2), r3=a(3), r4=a(4), r5=a(5), r6=a(6), r7=a(7);
    #pragma unroll
    for (int i = 8; i < 120; i += 8) {
        r0 += a(i);   r1 += a(i+1); r2 += a(i+2); r3 += a(i+3);
        r4 += a(i+4); r5 += a(i+5); r6 += a(i+6); r7 += a(i+7);
    }
    float res = ((r0 + r1) + (r2 + r3)) + ((r4 + r5) + (r6 + r7));
    res += a(120); res += a(121); res += a(122); res += a(123); res += a(124); res += a(125);
    return res;
}

// Mixed-precision np mirror (PROVEN bit-exact in round 11): mu1/var1 in f32,
// promotion to f64 at "var + 1e-5", f64 downstream. Do not alter op order.
__global__ __launch_bounds__(TPB) void bnn_v11(
    const float* __restrict__ x,
    const float* __restrict__ conv_w,
    const float* __restrict__ gn1_w, const float* __restrict__ gn1_b,
    const float* __restrict__ gn2_w, const float* __restrict__ gn2_b,
    const float* __restrict__ lin_w, const float* __restrict__ lin_b,
    const float* __restrict__ gn3_w, const float* __restrict__ gn3_b,
    float* __restrict__ out, int nrows)
{
    #pragma clang fp contract(off)
    __shared__ ulonglong2 s_xs[TPB];    // per-row x sign bits (elems 0-63, 64-125)
    __shared__ ulonglong2 s_xn[TPB];    // per-row x nonzero bits
    __shared__ ulonglong2 s_ws[FDIM];   // conv_w row sign bits
    __shared__ ulonglong2 s_wn[FDIM];   // conv_w row nonzero bits
    __shared__ float2 s_g1[FDIM];
    __shared__ float2 s_g2[FDIM];
    __shared__ int8_t s_sl0[128];       // sign(lin_w[0][f])
    __shared__ int8_t s_sl1[128];       // sign(lin_w[1][f])
    __shared__ int s_flags;             // 2: gn1 nontrivial, 4: gn2 nontrivial

    const int t = threadIdx.x;
    const int lane = t & 63;
    const int wv = t >> 6;
    const int64_t row0 = (int64_t)blockIdx.x * TPB;
    const int64_t row = row0 + t;
    const bool rowOK = row < (int64_t)nrows;

    if (t == 0) s_flags = 0;
    __syncthreads();

    // ---- pack conv_w rows: one wave per row, coalesced loads + ballots ----
    // bit f of word0 = lane f's element; word1 bit l = element 64+l (l<62)
    for (int r = wv; r < FDIM; r += 4) {
        const float* wr = conv_w + (size_t)r * FDIM;
        float v0 = wr[lane];
        float v1 = (lane < FDIM - 64) ? wr[64 + lane] : 0.f;
        uint64_t ss0 = __ballot(v0 < 0.f);
        uint64_t nn0 = __ballot(v0 != 0.f);
        uint64_t ss1 = __ballot(v1 < 0.f);
        uint64_t nn1 = __ballot(v1 != 0.f);
        if (lane == 0) {
            s_ws[r] = make_ulonglong2(ss0, ss1);
            s_wn[r] = make_ulonglong2(nn0, nn1);
        }
    }

    // ---- pack x rows: wave wv packs rows [wv*64, wv*64+64), coalesced ----
    #pragma unroll 4
    for (int k = 0; k < 64; ++k) {
        int lr = (wv << 6) + k;
        int64_t r = row0 + lr;
        bool ok = r < (int64_t)nrows;          // uniform across the wave
        const float* xr = x + r * FDIM;
        float v0 = ok ? xr[lane] : 0.f;
        float v1 = (ok && lane < FDIM - 64) ? xr[64 + lane] : 0.f;
        uint64_t ss0 = __ballot(v0 < 0.f);
        uint64_t nn0 = __ballot(v0 != 0.f);
        uint64_t ss1 = __ballot(v1 < 0.f);
        uint64_t nn1 = __ballot(v1 != 0.f);
        if (lane == 0) {
            s_xs[lr] = make_ulonglong2(ss0, ss1);
            s_xn[lr] = make_ulonglong2(nn0, nn1);
        }
    }

    // ---- params ----
    if (t < FDIM) {
        float g1wv = gn1_w[t], g1bv = gn1_b[t];
        float g2wv = gn2_w[t], g2bv = gn2_b[t];
        s_g1[t] = make_float2(g1wv, g1bv);
        s_g2[t] = make_float2(g2wv, g2bv);
        if (g1wv != 1.f || g1bv != 0.f) atomicOr(&s_flags, 2);
        if (g2wv != 1.f || g2bv != 0.f) atomicOr(&s_flags, 4);
        float l0 = lin_w[t], l1 = lin_w[FDIM + t];
        s_sl0[t] = (int8_t)((l0 > 0.f) - (l0 < 0.f));
        s_sl1[t] = (int8_t)((l1 > 0.f) - (l1 < 0.f));
    }
    __syncthreads();
    const int flags = s_flags;

    // ---- own row's masks ----
    const ulonglong2 xs = s_xs[t];
    const ulonglong2 xn = s_xn[t];

    // ---- h[c] via XOR-popcount into REGISTERS (unified wn-masked form) ----
    // When w has no zeros, wn = full mask and this equals the Kx - 2*pc form.
    uint32_t hreg[32];
    int sum = 0;
    #pragma unroll
    for (int g = 0; g < 32; ++g) {
        uint32_t pack = 0;
        #pragma unroll
        for (int j = 0; j < 4; ++j) {
            const int cc = 4 * g + j;
            if (cc < FDIM) {
                ulonglong2 w = s_ws[cc];
                ulonglong2 wn = s_wn[cc];
                uint64_t m0 = xn.x & wn.x, m1 = xn.y & wn.y;
                int pm = __popcll(m0) + __popcll(m1);
                int pc = __popcll((xs.x ^ w.x) & m0) + __popcll((xs.y ^ w.y) & m1);
                int h = pm - 2 * pc;
                sum += h;
                pack |= (uint32_t)(h & 255) << (8 * j);
            }
        }
        hreg[g] = pack;
    }

    auto hget = [&](int i) -> int {   // i is compile-time constant at every call site
        return (int)(int8_t)((hreg[i >> 2] >> ((i & 3) << 3)) & 255u);
    };

    // ---- GN1 stats in f32 (np.mean keeps dtype), pairwise trees ----
    const float mu1f = (float)sum / 126.0f;       // pairwise f32 sum of ints is exact
    const float var1f = pw126f([&](int i) -> float {
        #pragma clang fp contract(off)
        float e = (float)hget(i) - mu1f;
        return e * e;
    }) / 126.0f;
    // var1(f32) + 1e-5 (f64 literal) promotes -> f64 from here on
    const double r1 = 1.0 / sqrt((double)var1f + 1e-5);

    int ip0 = 0, ip1 = 0;
    if (!(flags & 6)) {
        // gamma=1, beta=0 (verified on-device): sign chain reduces to sign(c1 - mu2)
        auto c1f = [&](int i) -> double {
            #pragma clang fp contract(off)
            float e32 = (float)hget(i) - mu1f;
            double y = (double)e32 * r1;
            return fmin(fmax(y, -1.0), 1.0);
        };
        const double mu2 = pw126d(c1f) / 126.0;
        #pragma unroll
        for (int c = 0; c < FDIM; ++c) {
            double z = c1f(c) - mu2;
            int hb = (z > 0.0) - (z < 0.0);
            ip0 += hb * (int)s_sl0[c];
            ip1 += hb * (int)s_sl1[c];
        }
    } else {
        // general path (not taken for this data): recompute h from masks, rolled
        auto hdyn = [&](int c) -> int {
            ulonglong2 w = s_ws[c];
            ulonglong2 wn = s_wn[c];
            uint64_t m0 = xn.x & wn.x, m1 = xn.y & wn.y;
            int pm = __popcll(m0) + __popcll(m1);
            int pc = __popcll((xs.x ^ w.x) & m0) + __popcll((xs.y ^ w.y) & m1);
            return pm - 2 * pc;
        };
        auto c1f = [&](int i) -> double {
            #pragma clang fp contract(off)
            float e32 = (float)hdyn(i) - mu1f;
            float2 g = s_g1[i];
            double y = (((double)e32 * r1) * (double)g.x) + (double)g.y;
            return fmin(fmax(y, -1.0), 1.0);
        };
        const double mu2 = pw126d(c1f) / 126.0;
        const double var2 = pw126d([&](int i) -> double {
            #pragma clang fp contract(off)
            double e2 = c1f(i) - mu2;
            return e2 * e2;
        }) / 126.0;
        const double r2 = 1.0 / sqrt(var2 + 1e-5);
        for (int c = 0; c < FDIM; ++c) {
            double e2 = c1f(c) - mu2;
            float2 g2 = s_g2[c];
            double z = ((e2 * r2) * (double)g2.x) + (double)g2.y;
            int hb = (z > 0.0) - (z < 0.0);
            ip0 += hb * (int)s_sl0[c];
            ip1 += hb * (int)s_sl1[c];
        }
    }

    // ---- BNNLinear + GN3 in f64 (proven) ----
    if (rowOK) {
        double o0 = (double)ip0 + (double)lin_b[0];
        double o1 = (double)ip1 + (double)lin_b[1];
        double mu = (o0 + o1) / 2.0;
        double d0 = o0 - mu, d1 = o1 - mu;
        double var = ((d0 * d0) + (d1 * d1)) / 2.0;
        double r3 = 1.0 / sqrt(var + 1e-5);
        double q0 = ((d0 * r3) * (double)gn3_w[0]) + (double)gn3_b[0];
        double q1 = ((d1 * r3) * (double)gn3_w[1]) + (double)gn3_b[1];
        reinterpret_cast<float2*>(out)[row] = make_float2((float)q0, (float)q1);
    }
}

extern "C" void kernel_launch(void* const* d_in, const int* in_sizes, int n_in,
                              void* d_out, int out_size, void* d_ws, size_t ws_size,
                              hipStream_t stream) {
    const float* x      = (const float*)d_in[0];
    const float* conv_w = (const float*)d_in[1];
    const float* gn1_w  = (const float*)d_in[2];
    const float* gn1_b  = (const float*)d_in[3];
    const float* gn2_w  = (const float*)d_in[4];
    const float* gn2_b  = (const float*)d_in[5];
    const float* lin_w  = (const float*)d_in[6];
    const float* lin_b  = (const float*)d_in[7];
    const float* gn3_w  = (const float*)d_in[8];
    const float* gn3_b  = (const float*)d_in[9];

    int nrows = in_sizes[0] / FDIM;
    int nblocks = (nrows + TPB - 1) / TPB;
    bnn_v11<<<nblocks, TPB, 0, stream>>>(x, conv_w, gn1_w, gn1_b, gn2_w, gn2_b,
                                         lin_w, lin_b, gn3_w, gn3_b,
                                         (float*)d_out, nrows);
}

// Round 13
// 112.170 us; speedup vs baseline: 1.6673x; 1.6673x over previous
//
#include <hip/hip_runtime.h>
#include <stdint.h>
#include <math.h>

#define FDIM 126
#define TPB 256

// numpy pairwise_sum for n=126 (n <= PW_BLOCKSIZE=128 branch), bit-exact trees.
// Rolled: a(i) must accept runtime i (it recomputes from registers + uniform LDS).
template <typename F>
__device__ __forceinline__ double pw126d(F a) {
    #pragma clang fp contract(off)
    double r0=a(0), r1=a(1), r2=a(2), r3=a(3), r4=a(4), r5=a(5), r6=a(6), r7=a(7);
    for (int i = 8; i < 120; i += 8) {
        r0 += a(i);   r1 += a(i+1); r2 += a(i+2); r3 += a(i+3);
        r4 += a(i+4); r5 += a(i+5); r6 += a(i+6); r7 += a(i+7);
    }
    double res = ((r0 + r1) + (r2 + r3)) + ((r4 + r5) + (r6 + r7));
    res += a(120); res += a(121); res += a(122); res += a(123); res += a(124); res += a(125);
    return res;
}
template <typename F>
__device__ __forceinline__ float pw126f(F a) {
    #pragma clang fp contract(off)
    float r0=a(0), r1=a(1), r2=a(2), r3=a(3), r4=a(4), r5=a(5), r6=a(6), r7=a(7);
    for (int i = 8; i < 120; i += 8) {
        r0 += a(i);   r1 += a(i+1); r2 += a(i+2); r3 += a(i+3);
        r4 += a(i+4); r5 += a(i+5); r6 += a(i+6); r7 += a(i+7);
    }
    float res = ((r0 + r1) + (r2 + r3)) + ((r4 + r5) + (r6 + r7));
    res += a(120); res += a(121); res += a(122); res += a(123); res += a(124); res += a(125);
    return res;
}

// Mixed-precision np mirror (PROVEN bit-exact, rounds 11/12): f32 mean/var,
// promote to f64 at "var + 1e-5", f64 downstream. Do not alter fp op order.
// h is never stored: recomputed per use from register masks + uniform LDS w.
__global__ __launch_bounds__(TPB, 8) void bnn_v13(
    const float* __restrict__ x,
    const float* __restrict__ conv_w,
    const float* __restrict__ gn1_w, const float* __restrict__ gn1_b,
    const float* __restrict__ gn2_w, const float* __restrict__ gn2_b,
    const float* __restrict__ lin_w, const float* __restrict__ lin_b,
    const float* __restrict__ gn3_w, const float* __restrict__ gn3_b,
    float* __restrict__ out, int nrows)
{
    #pragma clang fp contract(off)
    __shared__ ulonglong2 s_ws[FDIM];   // conv_w row sign bits (f 0-63, 64-125)
    __shared__ ulonglong2 s_wn[FDIM];   // conv_w row nonzero bits
    __shared__ ulonglong2 s_xs[TPB];    // x sign bits (staging; read back once)
    __shared__ ulonglong2 s_xn[TPB];    // x nonzero bits
    __shared__ float2 s_g1[FDIM];
    __shared__ float2 s_g2[FDIM];
    __shared__ int8_t s_sl0[128];       // sign(lin_w[0][f])
    __shared__ int8_t s_sl1[128];       // sign(lin_w[1][f])
    __shared__ int s_flags;             // 1: w has zeros, 2: gn1 nontrivial, 4: gn2 nontrivial

    const int t = threadIdx.x;
    const int lane = t & 63;
    const int wv = t >> 6;
    const int64_t row0 = (int64_t)blockIdx.x * TPB;
    const int64_t row = row0 + t;
    const bool rowOK = row < (int64_t)nrows;

    if (t == 0) s_flags = 0;
    __syncthreads();

    // ---- pack conv_w rows: one wave per row, coalesced loads + ballots ----
    for (int r = wv; r < FDIM; r += 4) {
        const float* wr = conv_w + (size_t)r * FDIM;
        float v0 = wr[lane];
        float v1 = (lane < FDIM - 64) ? wr[64 + lane] : 0.f;
        uint64_t ss0 = __ballot(v0 < 0.f);
        uint64_t nn0 = __ballot(v0 != 0.f);
        uint64_t ss1 = __ballot(v1 < 0.f);
        uint64_t nn1 = __ballot(v1 != 0.f);
        if (lane == 0) {
            s_ws[r] = make_ulonglong2(ss0, ss1);
            s_wn[r] = make_ulonglong2(nn0, nn1);
            if (__popcll(nn0) + __popcll(nn1) != FDIM) atomicOr(&s_flags, 1);
        }
    }

    // ---- pack x rows: wave wv packs rows [wv*64, wv*64+64), coalesced ----
    #pragma unroll 4
    for (int k = 0; k < 64; ++k) {
        int lr = (wv << 6) + k;
        int64_t r = row0 + lr;
        bool ok = r < (int64_t)nrows;          // uniform across the wave
        const float* xr = x + r * FDIM;
        float v0 = ok ? xr[lane] : 0.f;
        float v1 = (ok && lane < FDIM - 64) ? xr[64 + lane] : 0.f;
        uint64_t ss0 = __ballot(v0 < 0.f);
        uint64_t nn0 = __ballot(v0 != 0.f);
        uint64_t ss1 = __ballot(v1 < 0.f);
        uint64_t nn1 = __ballot(v1 != 0.f);
        if (lane == 0) {
            s_xs[lr] = make_ulonglong2(ss0, ss1);
            s_xn[lr] = make_ulonglong2(nn0, nn1);
        }
    }

    // ---- params ----
    if (t < FDIM) {
        float g1wv = gn1_w[t], g1bv = gn1_b[t];
        float g2wv = gn2_w[t], g2bv = gn2_b[t];
        s_g1[t] = make_float2(g1wv, g1bv);
        s_g2[t] = make_float2(g2wv, g2bv);
        if (g1wv != 1.f || g1bv != 0.f) atomicOr(&s_flags, 2);
        if (g2wv != 1.f || g2bv != 0.f) atomicOr(&s_flags, 4);
        float l0 = lin_w[t], l1 = lin_w[FDIM + t];
        s_sl0[t] = (int8_t)((l0 > 0.f) - (l0 < 0.f));
        s_sl1[t] = (int8_t)((l1 > 0.f) - (l1 < 0.f));
    }
    __syncthreads();
    const int flags = s_flags;

    // ---- own row's masks into registers (8 VGPR) ----
    const ulonglong2 xs = s_xs[t];
    const ulonglong2 xn = s_xn[t];
    const int Kx = __popcll(xn.x) + __popcll(xn.y);

    if (!(flags & 7)) {
        // ======== fast path: w has no zeros, gn1/gn2 trivial ========
        // h_c = Kx - 2*popc((xs^ws_c)&xn)  -- one uniform b128 LDS read per use
        auto hfast = [&](int c) -> int {
            ulonglong2 w = s_ws[c];
            int pc = __popcll((xs.x ^ w.x) & xn.x) + __popcll((xs.y ^ w.y) & xn.y);
            return Kx - 2 * pc;
        };

        int sum = 0;
        #pragma unroll 4
        for (int c = 0; c < FDIM; ++c) sum += hfast(c);

        const float mu1f = (float)sum / 126.0f;      // pairwise f32 int sum is exact
        const float var1f = pw126f([&](int i) -> float {
            #pragma clang fp contract(off)
            float e = (float)hfast(i) - mu1f;
            return e * e;
        }) / 126.0f;
        const double r1 = 1.0 / sqrt((double)var1f + 1e-5);   // f64 literal promotes

        auto c1f = [&](int i) -> double {
            #pragma clang fp contract(off)
            float e32 = (float)hfast(i) - mu1f;
            double y = (double)e32 * r1;
            return fmin(fmax(y, -1.0), 1.0);
        };
        const double mu2 = pw126d(c1f) / 126.0;

        int ip0 = 0, ip1 = 0;
        #pragma unroll 4
        for (int c = 0; c < FDIM; ++c) {
            double z = c1f(c) - mu2;
            int hb = (z > 0.0) - (z < 0.0);
            ip0 += hb * (int)s_sl0[c];
            ip1 += hb * (int)s_sl1[c];
        }

        if (rowOK) {
            double o0 = (double)ip0 + (double)lin_b[0];
            double o1 = (double)ip1 + (double)lin_b[1];
            double mu = (o0 + o1) / 2.0;
            double d0 = o0 - mu, d1 = o1 - mu;
            double var = ((d0 * d0) + (d1 * d1)) / 2.0;
            double r3 = 1.0 / sqrt(var + 1e-5);
            double q0 = ((d0 * r3) * (double)gn3_w[0]) + (double)gn3_b[0];
            double q1 = ((d1 * r3) * (double)gn3_w[1]) + (double)gn3_b[1];
            reinterpret_cast<float2*>(out)[row] = make_float2((float)q0, (float)q1);
        }
    } else {
        // ======== general path (not taken for this data), same np mirror ========
        auto hdyn = [&](int c) -> int {
            ulonglong2 w = s_ws[c];
            ulonglong2 wn = s_wn[c];
            uint64_t m0 = xn.x & wn.x, m1 = xn.y & wn.y;
            int pm = __popcll(m0) + __popcll(m1);
            int pc = __popcll((xs.x ^ w.x) & m0) + __popcll((xs.y ^ w.y) & m1);
            return pm - 2 * pc;
        };
        int sum = 0;
        for (int c = 0; c < FDIM; ++c) sum += hdyn(c);
        const float mu1f = (float)sum / 126.0f;
        const float var1f = pw126f([&](int i) -> float {
            #pragma clang fp contract(off)
            float e = (float)hdyn(i) - mu1f;
            return e * e;
        }) / 126.0f;
        const double r1 = 1.0 / sqrt((double)var1f + 1e-5);

        auto c1f = [&](int i) -> double {
            #pragma clang fp contract(off)
            float e32 = (float)hdyn(i) - mu1f;
            float2 g = s_g1[i];
            double y = (((double)e32 * r1) * (double)g.x) + (double)g.y;
            return fmin(fmax(y, -1.0), 1.0);
        };
        const double mu2 = pw126d(c1f) / 126.0;
        const double var2 = pw126d([&](int i) -> double {
            #pragma clang fp contract(off)
            double e2 = c1f(i) - mu2;
            return e2 * e2;
        }) / 126.0;
        const double r2 = 1.0 / sqrt(var2 + 1e-5);

        int ip0 = 0, ip1 = 0;
        for (int c = 0; c < FDIM; ++c) {
            double e2 = c1f(c) - mu2;
            float2 g2 = s_g2[c];
            double z = ((e2 * r2) * (double)g2.x) + (double)g2.y;  // clip keeps sign
            int hb = (z > 0.0) - (z < 0.0);
            ip0 += hb * (int)s_sl0[c];
            ip1 += hb * (int)s_sl1[c];
        }

        if (rowOK) {
            double o0 = (double)ip0 + (double)lin_b[0];
            double o1 = (double)ip1 + (double)lin_b[1];
            double mu = (o0 + o1) / 2.0;
            double d0 = o0 - mu, d1 = o1 - mu;
            double var = ((d0 * d0) + (d1 * d1)) / 2.0;
            double r3 = 1.0 / sqrt(var + 1e-5);
            double q0 = ((d0 * r3) * (double)gn3_w[0]) + (double)gn3_b[0];
            double q1 = ((d1 * r3) * (double)gn3_w[1]) + (double)gn3_b[1];
            reinterpret_cast<float2*>(out)[row] = make_float2((float)q0, (float)q1);
        }
    }
}

extern "C" void kernel_launch(void* const* d_in, const int* in_sizes, int n_in,
                              void* d_out, int out_size, void* d_ws, size_t ws_size,
                              hipStream_t stream) {
    const float* x      = (const float*)d_in[0];
    const float* conv_w = (const float*)d_in[1];
    const float* gn1_w  = (const float*)d_in[2];
    const float* gn1_b  = (const float*)d_in[3];
    const float* gn2_w  = (const float*)d_in[4];
    const float* gn2_b  = (const float*)d_in[5];
    const float* lin_w  = (const float*)d_in[6];
    const float* lin_b  = (const float*)d_in[7];
    const float* gn3_w  = (const float*)d_in[8];
    const float* gn3_b  = (const float*)d_in[9];

    int nrows = in_sizes[0] / FDIM;
    int nblocks = (nrows + TPB - 1) / TPB;
    bnn_v13<<<nblocks, TPB, 0, stream>>>(x, conv_w, gn1_w, gn1_b, gn2_w, gn2_b,
                                         lin_w, lin_b, gn3_w, gn3_b,
                                         (float*)d_out, nrows);
}

// Round 14
// 81.782 us; speedup vs baseline: 2.2868x; 1.3716x over previous
//
#include <hip/hip_runtime.h>
#include <stdint.h>
#include <math.h>

#define FDIM 126
#define TPB 256

// numpy pairwise_sum for n=126 (n <= PW_BLOCKSIZE=128 branch), bit-exact trees.
// Rolled (v10-proven): keeps VGPR pressure low; a(i) takes runtime i.
template <typename F>
__device__ __forceinline__ double pw126d(F a) {
    #pragma clang fp contract(off)
    double r0=a(0), r1=a(1), r2=a(2), r3=a(3), r4=a(4), r5=a(5), r6=a(6), r7=a(7);
    for (int i = 8; i < 120; i += 8) {
        r0 += a(i);   r1 += a(i+1); r2 += a(i+2); r3 += a(i+3);
        r4 += a(i+4); r5 += a(i+5); r6 += a(i+6); r7 += a(i+7);
    }
    double res = ((r0 + r1) + (r2 + r3)) + ((r4 + r5) + (r6 + r7));
    res += a(120); res += a(121); res += a(122); res += a(123); res += a(124); res += a(125);
    return res;
}
template <typename F>
__device__ __forceinline__ float pw126f(F a) {
    #pragma clang fp contract(off)
    float r0=a(0), r1=a(1), r2=a(2), r3=a(3), r4=a(4), r5=a(5), r6=a(6), r7=a(7);
    for (int i = 8; i < 120; i += 8) {
        r0 += a(i);   r1 += a(i+1); r2 += a(i+2); r3 += a(i+3);
        r4 += a(i+4); r5 += a(i+5); r6 += a(i+6); r7 += a(i+7);
    }
    float res = ((r0 + r1) + (r2 + r3)) + ((r4 + r5) + (r6 + r7));
    res += a(120); res += a(121); res += a(122); res += a(123); res += a(124); res += a(125);
    return res;
}

// v14 = v13's ballot-coalesced loader + v10's compute-once h-in-LDS passes.
// LDS overlay: x-mask staging (8KB) shares the pool with s_h (32KB); staging is
// consumed into registers before h writes (barrier between).
// Numeric chain: PROVEN bit-exact mixed-precision np mirror (rounds 11-13).
__global__ __launch_bounds__(TPB) void bnn_v14(
    const float* __restrict__ x,
    const float* __restrict__ conv_w,
    const float* __restrict__ gn1_w, const float* __restrict__ gn1_b,
    const float* __restrict__ gn2_w, const float* __restrict__ gn2_b,
    const float* __restrict__ lin_w, const float* __restrict__ lin_b,
    const float* __restrict__ gn3_w, const float* __restrict__ gn3_b,
    float* __restrict__ out, int nrows)
{
    #pragma clang fp contract(off)
    __shared__ ulonglong2 s_ws[FDIM];   // conv_w row sign bits (f 0-63, 64-125)
    __shared__ ulonglong2 s_wn[FDIM];   // conv_w row nonzero bits
    __shared__ float2 s_g1[FDIM];
    __shared__ float2 s_g2[FDIM];
    __shared__ int8_t s_sl0[128];       // sign(lin_w[0][f])
    __shared__ int8_t s_sl1[128];       // sign(lin_w[1][f])
    __shared__ int s_flags;             // 1: w zeros, 2: gn1 nontrivial, 4: gn2 nontrivial
    __shared__ __align__(16) uint8_t s_pool[TPB * 128];  // overlay: staging then s_h

    ulonglong2* s_xs = (ulonglong2*)s_pool;            // [TPB], 4KB
    ulonglong2* s_xn = (ulonglong2*)(s_pool + 4096);   // [TPB], 4KB
    uint32_t*   s_h  = (uint32_t*)s_pool;              // [32*TPB], 32KB (after barrier)

    const int t = threadIdx.x;
    const int lane = t & 63;
    const int wv = t >> 6;
    const int64_t row0 = (int64_t)blockIdx.x * TPB;
    const int64_t row = row0 + t;
    const bool rowOK = row < (int64_t)nrows;

    if (t == 0) s_flags = 0;
    __syncthreads();

    // ---- pack conv_w rows: one wave per row, coalesced loads + ballots ----
    for (int r = wv; r < FDIM; r += 4) {
        const float* wr = conv_w + (size_t)r * FDIM;
        float v0 = wr[lane];
        float v1 = (lane < FDIM - 64) ? wr[64 + lane] : 0.f;
        uint64_t ss0 = __ballot(v0 < 0.f);
        uint64_t nn0 = __ballot(v0 != 0.f);
        uint64_t ss1 = __ballot(v1 < 0.f);
        uint64_t nn1 = __ballot(v1 != 0.f);
        if (lane == 0) {
            s_ws[r] = make_ulonglong2(ss0, ss1);
            s_wn[r] = make_ulonglong2(nn0, nn1);
            if (__popcll(nn0) + __popcll(nn1) != FDIM) atomicOr(&s_flags, 1);
        }
    }

    // ---- pack x rows: wave wv packs rows [wv*64, wv*64+64), coalesced ----
    #pragma unroll 4
    for (int k = 0; k < 64; ++k) {
        int lr = (wv << 6) + k;
        int64_t r = row0 + lr;
        bool ok = r < (int64_t)nrows;          // uniform across the wave
        const float* xr = x + r * FDIM;
        float v0 = ok ? xr[lane] : 0.f;
        float v1 = (ok && lane < FDIM - 64) ? xr[64 + lane] : 0.f;
        uint64_t ss0 = __ballot(v0 < 0.f);
        uint64_t nn0 = __ballot(v0 != 0.f);
        uint64_t ss1 = __ballot(v1 < 0.f);
        uint64_t nn1 = __ballot(v1 != 0.f);
        if (lane == 0) {
            s_xs[lr] = make_ulonglong2(ss0, ss1);
            s_xn[lr] = make_ulonglong2(nn0, nn1);
        }
    }

    // ---- params ----
    if (t < FDIM) {
        float g1wv = gn1_w[t], g1bv = gn1_b[t];
        float g2wv = gn2_w[t], g2bv = gn2_b[t];
        s_g1[t] = make_float2(g1wv, g1bv);
        s_g2[t] = make_float2(g2wv, g2bv);
        if (g1wv != 1.f || g1bv != 0.f) atomicOr(&s_flags, 2);
        if (g2wv != 1.f || g2bv != 0.f) atomicOr(&s_flags, 4);
        float l0 = lin_w[t], l1 = lin_w[FDIM + t];
        s_sl0[t] = (int8_t)((l0 > 0.f) - (l0 < 0.f));
        s_sl1[t] = (int8_t)((l1 > 0.f) - (l1 < 0.f));
    }
    __syncthreads();
    const int flags = s_flags;

    // ---- own row's masks into registers, then free the staging for s_h ----
    const ulonglong2 xs = s_xs[t];
    const ulonglong2 xn = s_xn[t];
    const int Kx = __popcll(xn.x) + __popcll(xn.y);
    __syncthreads();   // staging fully consumed; pool becomes s_h

    // ---- compute h ONCE, packed bytes into own s_h column; integer row sum ----
    int sum = 0;
    if (!(flags & 1)) {
        for (int g = 0; g < 32; ++g) {
            uint32_t pack = 0;
            #pragma unroll
            for (int j = 0; j < 4; ++j) {
                int cc = 4 * g + j;
                if (cc < FDIM) {
                    ulonglong2 w = s_ws[cc];
                    int pc = __popcll((xs.x ^ w.x) & xn.x) + __popcll((xs.y ^ w.y) & xn.y);
                    int h = Kx - 2 * pc;
                    sum += h;
                    pack |= (uint32_t)(h & 255) << (8 * j);
                }
            }
            s_h[g * TPB + t] = pack;
        }
    } else {
        for (int g = 0; g < 32; ++g) {
            uint32_t pack = 0;
            #pragma unroll
            for (int j = 0; j < 4; ++j) {
                int cc = 4 * g + j;
                if (cc < FDIM) {
                    ulonglong2 w = s_ws[cc];
                    ulonglong2 wn = s_wn[cc];
                    uint64_t m0 = xn.x & wn.x, m1 = xn.y & wn.y;
                    int pm = __popcll(m0) + __popcll(m1);
                    int pc = __popcll((xs.x ^ w.x) & m0) + __popcll((xs.y ^ w.y) & m1);
                    int h = pm - 2 * pc;
                    sum += h;
                    pack |= (uint32_t)(h & 255) << (8 * j);
                }
            }
            s_h[g * TPB + t] = pack;
        }
    }
    // no barrier needed: each thread reads only its own column s_h[*][t]

    auto hget = [&](int i) -> int {
        return (int)(int8_t)((s_h[(i >> 2) * TPB + t] >> ((i & 3) << 3)) & 255u);
    };

    // ---- GN1 stats in f32 (np.mean keeps dtype), pairwise trees (PROVEN) ----
    const float mu1f = (float)sum / 126.0f;
    const float var1f = pw126f([&](int i) -> float {
        #pragma clang fp contract(off)
        float e = (float)hget(i) - mu1f;
        return e * e;
    }) / 126.0f;
    const double r1 = 1.0 / sqrt((double)var1f + 1e-5);   // f64 literal promotes

    int ip0 = 0, ip1 = 0;
    if (!(flags & 6)) {
        auto c1f = [&](int i) -> double {
            #pragma clang fp contract(off)
            float e32 = (float)hget(i) - mu1f;
            double y = (double)e32 * r1;
            return fmin(fmax(y, -1.0), 1.0);
        };
        const double mu2 = pw126d(c1f) / 126.0;
        for (int c = 0; c < FDIM; ++c) {
            double z = c1f(c) - mu2;
            int hb = (z > 0.0) - (z < 0.0);
            ip0 += hb * (int)s_sl0[c];
            ip1 += hb * (int)s_sl1[c];
        }
    } else {
        auto c1f = [&](int i) -> double {
            #pragma clang fp contract(off)
            float e32 = (float)hget(i) - mu1f;
            float2 g = s_g1[i];
            double y = (((double)e32 * r1) * (double)g.x) + (double)g.y;
            return fmin(fmax(y, -1.0), 1.0);
        };
        const double mu2 = pw126d(c1f) / 126.0;
        const double var2 = pw126d([&](int i) -> double {
            #pragma clang fp contract(off)
            double e2 = c1f(i) - mu2;
            return e2 * e2;
        }) / 126.0;
        const double r2 = 1.0 / sqrt(var2 + 1e-5);
        for (int c = 0; c < FDIM; ++c) {
            double e2 = c1f(c) - mu2;
            float2 g2 = s_g2[c];
            double z = ((e2 * r2) * (double)g2.x) + (double)g2.y;
            int hb = (z > 0.0) - (z < 0.0);
            ip0 += hb * (int)s_sl0[c];
            ip1 += hb * (int)s_sl1[c];
        }
    }

    // ---- BNNLinear + GN3 in f64 (PROVEN) ----
    if (rowOK) {
        double o0 = (double)ip0 + (double)lin_b[0];
        double o1 = (double)ip1 + (double)lin_b[1];
        double mu = (o0 + o1) / 2.0;
        double d0 = o0 - mu, d1 = o1 - mu;
        double var = ((d0 * d0) + (d1 * d1)) / 2.0;
        double r3 = 1.0 / sqrt(var + 1e-5);
        double q0 = ((d0 * r3) * (double)gn3_w[0]) + (double)gn3_b[0];
        double q1 = ((d1 * r3) * (double)gn3_w[1]) + (double)gn3_b[1];
        reinterpret_cast<float2*>(out)[row] = make_float2((float)q0, (float)q1);
    }
}

extern "C" void kernel_launch(void* const* d_in, const int* in_sizes, int n_in,
                              void* d_out, int out_size, void* d_ws, size_t ws_size,
                              hipStream_t stream) {
    const float* x      = (const float*)d_in[0];
    const float* conv_w = (const float*)d_in[1];
    const float* gn1_w  = (const float*)d_in[2];
    const float* gn1_b  = (const float*)d_in[3];
    const float* gn2_w  = (const float*)d_in[4];
    const float* gn2_b  = (const float*)d_in[5];
    const float* lin_w  = (const float*)d_in[6];
    const float* lin_b  = (const float*)d_in[7];
    const float* gn3_w  = (const float*)d_in[8];
    const float* gn3_b  = (const float*)d_in[9];

    int nrows = in_sizes[0] / FDIM;
    int nblocks = (nrows + TPB - 1) / TPB;
    bnn_v14<<<nblocks, TPB, 0, stream>>>(x, conv_w, gn1_w, gn1_b, gn2_w, gn2_b,
                                         lin_w, lin_b, gn3_w, gn3_b,
                                         (float*)d_out, nrows);
}

// Round 15
// 77.516 us; speedup vs baseline: 2.4127x; 1.0550x over previous
//
#include <hip/hip_runtime.h>
#include <stdint.h>
#include <math.h>

#define FDIM 126
#define TPB 256
#define BEXT(u, j) ((int)(int8_t)((u) >> ((j) * 8)))

// numpy pairwise_sum trees for the (never-taken) general path, rolled.
template <typename F>
__device__ __forceinline__ double pw126d(F a) {
    #pragma clang fp contract(off)
    double r0=a(0), r1=a(1), r2=a(2), r3=a(3), r4=a(4), r5=a(5), r6=a(6), r7=a(7);
    for (int i = 8; i < 120; i += 8) {
        r0 += a(i);   r1 += a(i+1); r2 += a(i+2); r3 += a(i+3);
        r4 += a(i+4); r5 += a(i+5); r6 += a(i+6); r7 += a(i+7);
    }
    double res = ((r0 + r1) + (r2 + r3)) + ((r4 + r5) + (r6 + r7));
    res += a(120); res += a(121); res += a(122); res += a(123); res += a(124); res += a(125);
    return res;
}

// v15 = v14 + dword-batched pass walks + integer-threshold sign pass.
// Numeric chain: PROVEN bit-exact mixed-precision np mirror (rounds 11-14).
__global__ __launch_bounds__(TPB) void bnn_v15(
    const float* __restrict__ x,
    const float* __restrict__ conv_w,
    const float* __restrict__ gn1_w, const float* __restrict__ gn1_b,
    const float* __restrict__ gn2_w, const float* __restrict__ gn2_b,
    const float* __restrict__ lin_w, const float* __restrict__ lin_b,
    const float* __restrict__ gn3_w, const float* __restrict__ gn3_b,
    float* __restrict__ out, int nrows)
{
    #pragma clang fp contract(off)
    __shared__ ulonglong2 s_ws[FDIM];   // conv_w row sign bits (f 0-63, 64-125)
    __shared__ ulonglong2 s_wn[FDIM];   // conv_w row nonzero bits
    __shared__ float2 s_g1[FDIM];
    __shared__ float2 s_g2[FDIM];
    __shared__ int8_t s_sl0[128];       // sign(lin_w[0][f])
    __shared__ int8_t s_sl1[128];       // sign(lin_w[1][f])
    __shared__ int s_flags;             // 1: w zeros, 2: gn1 nontrivial, 4: gn2 nontrivial
    __shared__ __align__(16) uint8_t s_pool[TPB * 128];  // overlay: staging then s_h

    ulonglong2* s_xs = (ulonglong2*)s_pool;            // [TPB], 4KB
    ulonglong2* s_xn = (ulonglong2*)(s_pool + 4096);   // [TPB], 4KB
    uint32_t*   s_h  = (uint32_t*)s_pool;              // [32*TPB], 32KB (after barrier)

    const int t = threadIdx.x;
    const int lane = t & 63;
    const int wv = t >> 6;
    const int64_t row0 = (int64_t)blockIdx.x * TPB;
    const int64_t row = row0 + t;
    const bool rowOK = row < (int64_t)nrows;

    if (t == 0) s_flags = 0;
    __syncthreads();

    // ---- pack conv_w rows: one wave per row, coalesced loads + ballots ----
    for (int r = wv; r < FDIM; r += 4) {
        const float* wr = conv_w + (size_t)r * FDIM;
        float v0 = wr[lane];
        float v1 = (lane < FDIM - 64) ? wr[64 + lane] : 0.f;
        uint64_t ss0 = __ballot(v0 < 0.f);
        uint64_t nn0 = __ballot(v0 != 0.f);
        uint64_t ss1 = __ballot(v1 < 0.f);
        uint64_t nn1 = __ballot(v1 != 0.f);
        if (lane == 0) {
            s_ws[r] = make_ulonglong2(ss0, ss1);
            s_wn[r] = make_ulonglong2(nn0, nn1);
            if (__popcll(nn0) + __popcll(nn1) != FDIM) atomicOr(&s_flags, 1);
        }
    }

    // ---- pack x rows: wave wv packs rows [wv*64, wv*64+64), coalesced ----
    #pragma unroll 4
    for (int k = 0; k < 64; ++k) {
        int lr = (wv << 6) + k;
        int64_t r = row0 + lr;
        bool ok = r < (int64_t)nrows;          // uniform across the wave
        const float* xr = x + r * FDIM;
        float v0 = ok ? xr[lane] : 0.f;
        float v1 = (ok && lane < FDIM - 64) ? xr[64 + lane] : 0.f;
        uint64_t ss0 = __ballot(v0 < 0.f);
        uint64_t nn0 = __ballot(v0 != 0.f);
        uint64_t ss1 = __ballot(v1 < 0.f);
        uint64_t nn1 = __ballot(v1 != 0.f);
        if (lane == 0) {
            s_xs[lr] = make_ulonglong2(ss0, ss1);
            s_xn[lr] = make_ulonglong2(nn0, nn1);
        }
    }

    // ---- params ----
    if (t < FDIM) {
        float g1wv = gn1_w[t], g1bv = gn1_b[t];
        float g2wv = gn2_w[t], g2bv = gn2_b[t];
        s_g1[t] = make_float2(g1wv, g1bv);
        s_g2[t] = make_float2(g2wv, g2bv);
        if (g1wv != 1.f || g1bv != 0.f) atomicOr(&s_flags, 2);
        if (g2wv != 1.f || g2bv != 0.f) atomicOr(&s_flags, 4);
        float l0 = lin_w[t], l1 = lin_w[FDIM + t];
        s_sl0[t] = (int8_t)((l0 > 0.f) - (l0 < 0.f));
        s_sl1[t] = (int8_t)((l1 > 0.f) - (l1 < 0.f));
    }
    __syncthreads();
    const int flags = s_flags;

    // ---- own row's masks into registers, then free the staging for s_h ----
    const ulonglong2 xs = s_xs[t];
    const ulonglong2 xn = s_xn[t];
    const int Kx = __popcll(xn.x) + __popcll(xn.y);
    __syncthreads();   // staging fully consumed; pool becomes s_h

    // ---- compute h ONCE, packed bytes into own s_h column; integer row sum ----
    int sum = 0;
    if (!(flags & 1)) {
        for (int g = 0; g < 32; ++g) {
            uint32_t pack = 0;
            #pragma unroll
            for (int j = 0; j < 4; ++j) {
                int cc = 4 * g + j;
                if (cc < FDIM) {
                    ulonglong2 w = s_ws[cc];
                    int pc = __popcll((xs.x ^ w.x) & xn.x) + __popcll((xs.y ^ w.y) & xn.y);
                    int h = Kx - 2 * pc;
                    sum += h;
                    pack |= (uint32_t)(h & 255) << (8 * j);
                }
            }
            s_h[g * TPB + t] = pack;
        }
    } else {
        for (int g = 0; g < 32; ++g) {
            uint32_t pack = 0;
            #pragma unroll
            for (int j = 0; j < 4; ++j) {
                int cc = 4 * g + j;
                if (cc < FDIM) {
                    ulonglong2 w = s_ws[cc];
                    ulonglong2 wn = s_wn[cc];
                    uint64_t m0 = xn.x & wn.x, m1 = xn.y & wn.y;
                    int pm = __popcll(m0) + __popcll(m1);
                    int pc = __popcll((xs.x ^ w.x) & m0) + __popcll((xs.y ^ w.y) & m1);
                    int h = pm - 2 * pc;
                    sum += h;
                    pack |= (uint32_t)(h & 255) << (8 * j);
                }
            }
            s_h[g * TPB + t] = pack;
        }
    }
    // no barrier needed: each thread reads only its own column s_h[*][t]

    auto hdw = [&](int g) -> uint32_t { return s_h[g * TPB + t]; };
    auto hget = [&](int i) -> int { return BEXT(hdw(i >> 2), i & 3); };

    // ---- GN1 var in f32: np pairwise tree, dword-batched (order preserved) ----
    const float mu1f = (float)sum / 126.0f;
    float var1f;
    {
        uint32_t u0 = hdw(0), u1 = hdw(1);
        float e;
        e = (float)BEXT(u0,0) - mu1f; float q0 = e*e;
        e = (float)BEXT(u0,1) - mu1f; float q1 = e*e;
        e = (float)BEXT(u0,2) - mu1f; float q2 = e*e;
        e = (float)BEXT(u0,3) - mu1f; float q3 = e*e;
        e = (float)BEXT(u1,0) - mu1f; float q4 = e*e;
        e = (float)BEXT(u1,1) - mu1f; float q5 = e*e;
        e = (float)BEXT(u1,2) - mu1f; float q6 = e*e;
        e = (float)BEXT(u1,3) - mu1f; float q7 = e*e;
        for (int k = 1; k < 15; ++k) {
            uint32_t a0 = hdw(2*k), a1 = hdw(2*k + 1);
            e = (float)BEXT(a0,0) - mu1f; q0 += e*e;
            e = (float)BEXT(a0,1) - mu1f; q1 += e*e;
            e = (float)BEXT(a0,2) - mu1f; q2 += e*e;
            e = (float)BEXT(a0,3) - mu1f; q3 += e*e;
            e = (float)BEXT(a1,0) - mu1f; q4 += e*e;
            e = (float)BEXT(a1,1) - mu1f; q5 += e*e;
            e = (float)BEXT(a1,2) - mu1f; q6 += e*e;
            e = (float)BEXT(a1,3) - mu1f; q7 += e*e;
        }
        float res = ((q0 + q1) + (q2 + q3)) + ((q4 + q5) + (q6 + q7));
        uint32_t u30 = hdw(30), u31 = hdw(31);
        e = (float)BEXT(u30,0) - mu1f; res += e*e;
        e = (float)BEXT(u30,1) - mu1f; res += e*e;
        e = (float)BEXT(u30,2) - mu1f; res += e*e;
        e = (float)BEXT(u30,3) - mu1f; res += e*e;
        e = (float)BEXT(u31,0) - mu1f; res += e*e;
        e = (float)BEXT(u31,1) - mu1f; res += e*e;
        var1f = res / 126.0f;
    }
    const double r1 = 1.0 / sqrt((double)var1f + 1e-5);   // f64 literal promotes

    // c1 as a function of the INTEGER h (identical ops to the proven c1f)
    auto c1ofh = [&](int hv) -> double {
        #pragma clang fp contract(off)
        float e32 = (float)hv - mu1f;
        double y = (double)e32 * r1;
        return fmin(fmax(y, -1.0), 1.0);
    };

    int ip0 = 0, ip1 = 0;
    if (!(flags & 6)) {
        // ---- mu2: f64 np pairwise tree, dword-batched (order preserved) ----
        double mu2;
        {
            uint32_t u0 = hdw(0), u1 = hdw(1);
            double q0 = c1ofh(BEXT(u0,0)), q1 = c1ofh(BEXT(u0,1));
            double q2 = c1ofh(BEXT(u0,2)), q3 = c1ofh(BEXT(u0,3));
            double q4 = c1ofh(BEXT(u1,0)), q5 = c1ofh(BEXT(u1,1));
            double q6 = c1ofh(BEXT(u1,2)), q7 = c1ofh(BEXT(u1,3));
            for (int k = 1; k < 15; ++k) {
                uint32_t a0 = hdw(2*k), a1 = hdw(2*k + 1);
                q0 += c1ofh(BEXT(a0,0)); q1 += c1ofh(BEXT(a0,1));
                q2 += c1ofh(BEXT(a0,2)); q3 += c1ofh(BEXT(a0,3));
                q4 += c1ofh(BEXT(a1,0)); q5 += c1ofh(BEXT(a1,1));
                q6 += c1ofh(BEXT(a1,2)); q7 += c1ofh(BEXT(a1,3));
            }
            double res = ((q0 + q1) + (q2 + q3)) + ((q4 + q5) + (q6 + q7));
            uint32_t u30 = hdw(30), u31 = hdw(31);
            res += c1ofh(BEXT(u30,0)); res += c1ofh(BEXT(u30,1));
            res += c1ofh(BEXT(u30,2)); res += c1ofh(BEXT(u30,3));
            res += c1ofh(BEXT(u31,0)); res += c1ofh(BEXT(u31,1));
            mu2 = res / 126.0;
        }

        // ---- integer thresholds: c1ofh is weakly monotone in hv (IEEE rounding
        // preserves order; r1 > 0), so the sign classes of c1(h)-mu2 are integer
        // intervals. vge = min{v: c1(v) >= mu2}, vgt = min{v: c1(v) > mu2}.
        const double c127 = c1ofh(127);
        int lo1 = -127, hi1 = 127, lo2 = -127, hi2 = 127;
        #pragma unroll
        for (int it = 0; it < 8; ++it) {
            int m1 = (lo1 + hi1) >> 1;
            bool ge = (c1ofh(m1) >= mu2);
            hi1 = ge ? m1 : hi1;  lo1 = ge ? lo1 : m1 + 1;
            int m2 = (lo2 + hi2) >> 1;
            bool gt = (c1ofh(m2) > mu2);
            hi2 = gt ? m2 : hi2;  lo2 = gt ? lo2 : m2 + 1;
        }
        const int vge = (c127 >= mu2) ? lo1 : 128;
        const int vgt = (c127 >  mu2) ? lo2 : 128;

        // ---- sign pass: pure integer compares (== f64 sign(c1-mu2), proven) ----
        for (int g = 0; g < 31; ++g) {
            uint32_t u = hdw(g);
            #pragma unroll
            for (int j = 0; j < 4; ++j) {
                int c = 4 * g + j;
                int hv = BEXT(u, j);
                int hb = (hv >= vgt) - (hv < vge);
                ip0 += hb * (int)s_sl0[c];
                ip1 += hb * (int)s_sl1[c];
            }
        }
        {
            uint32_t u = hdw(31);
            #pragma unroll
            for (int j = 0; j < 2; ++j) {
                int hv = BEXT(u, j);
                int hb = (hv >= vgt) - (hv < vge);
                ip0 += hb * (int)s_sl0[124 + j];
                ip1 += hb * (int)s_sl1[124 + j];
            }
        }
    } else {
        // ---- general path (not taken for this data): v14-verbatim np mirror ----
        auto c1f = [&](int i) -> double {
            #pragma clang fp contract(off)
            float e32 = (float)hget(i) - mu1f;
            float2 g = s_g1[i];
            double y = (((double)e32 * r1) * (double)g.x) + (double)g.y;
            return fmin(fmax(y, -1.0), 1.0);
        };
        const double mu2 = pw126d(c1f) / 126.0;
        const double var2 = pw126d([&](int i) -> double {
            #pragma clang fp contract(off)
            double e2 = c1f(i) - mu2;
            return e2 * e2;
        }) / 126.0;
        const double r2 = 1.0 / sqrt(var2 + 1e-5);
        for (int c = 0; c < FDIM; ++c) {
            double e2 = c1f(c) - mu2;
            float2 g2 = s_g2[c];
            double z = ((e2 * r2) * (double)g2.x) + (double)g2.y;
            int hb = (z > 0.0) - (z < 0.0);
            ip0 += hb * (int)s_sl0[c];
            ip1 += hb * (int)s_sl1[c];
        }
    }

    // ---- BNNLinear + GN3 in f64 (PROVEN) ----
    if (rowOK) {
        double o0 = (double)ip0 + (double)lin_b[0];
        double o1 = (double)ip1 + (double)lin_b[1];
        double mu = (o0 + o1) / 2.0;
        double d0 = o0 - mu, d1 = o1 - mu;
        double var = ((d0 * d0) + (d1 * d1)) / 2.0;
        double r3 = 1.0 / sqrt(var + 1e-5);
        double q0 = ((d0 * r3) * (double)gn3_w[0]) + (double)gn3_b[0];
        double q1 = ((d1 * r3) * (double)gn3_w[1]) + (double)gn3_b[1];
        reinterpret_cast<float2*>(out)[row] = make_float2((float)q0, (float)q1);
    }
}

extern "C" void kernel_launch(void* const* d_in, const int* in_sizes, int n_in,
                              void* d_out, int out_size, void* d_ws, size_t ws_size,
                              hipStream_t stream) {
    const float* x      = (const float*)d_in[0];
    const float* conv_w = (const float*)d_in[1];
    const float* gn1_w  = (const float*)d_in[2];
    const float* gn1_b  = (const float*)d_in[3];
    const float* gn2_w  = (const float*)d_in[4];
    const float* gn2_b  = (const float*)d_in[5];
    const float* lin_w  = (const float*)d_in[6];
    const float* lin_b  = (const float*)d_in[7];
    const float* gn3_w  = (const float*)d_in[8];
    const float* gn3_b  = (const float*)d_in[9];

    int nrows = in_sizes[0] / FDIM;
    int nblocks = (nrows + TPB - 1) / TPB;
    bnn_v15<<<nblocks, TPB, 0, stream>>>(x, conv_w, gn1_w, gn1_b, gn2_w, gn2_b,
                                         lin_w, lin_b, gn3_w, gn3_b,
                                         (float*)d_out, nrows);
}

// Round 16
// 69.009 us; speedup vs baseline: 2.7101x; 1.1233x over previous
//
#include <hip/hip_runtime.h>
#include <stdint.h>
#include <math.h>

#define FDIM 126
#define TPB 256
#define BEXT(u, j) ((int)(int8_t)((u) >> ((j) * 8)))

// numpy pairwise_sum tree (n=126), f64 — used by never-taken general path.
template <typename F>
__device__ __forceinline__ double pw126d(F a) {
    #pragma clang fp contract(off)
    double r0=a(0), r1=a(1), r2=a(2), r3=a(3), r4=a(4), r5=a(5), r6=a(6), r7=a(7);
    for (int i = 8; i < 120; i += 8) {
        r0 += a(i);   r1 += a(i+1); r2 += a(i+2); r3 += a(i+3);
        r4 += a(i+4); r5 += a(i+5); r6 += a(i+6); r7 += a(i+7);
    }
    double res = ((r0 + r1) + (r2 + r3)) + ((r4 + r5) + (r6 + r7));
    res += a(120); res += a(121); res += a(122); res += a(123); res += a(124); res += a(125);
    return res;
}

// ================= K1: pack x (and conv_w) into bitmasks in d_ws =================
// Each wave packs 32 rows -> 8192 waves -> 32 waves/CU (100% occupancy), no LDS.
__global__ __launch_bounds__(TPB) void bnn_pack(
    const float* __restrict__ x, const float* __restrict__ conv_w,
    ulonglong2* __restrict__ wbuf,    // [252]: ws[126], then wn[126]
    ulonglong2* __restrict__ xbuf,    // [2*nrows]: row i -> xs at 2i, xn at 2i+1
    int nrows)
{
    const int t = threadIdx.x, lane = t & 63, wv = t >> 6;
    const int64_t row0 = (int64_t)blockIdx.x * 128;

    if (blockIdx.x == 0) {
        for (int r = wv; r < FDIM; r += 4) {
            const float* wr = conv_w + (size_t)r * FDIM;
            float v0 = wr[lane];
            float v1 = (lane < FDIM - 64) ? wr[64 + lane] : 0.f;
            uint64_t ss0 = __ballot(v0 < 0.f);
            uint64_t nn0 = __ballot(v0 != 0.f);
            uint64_t ss1 = __ballot(v1 < 0.f);
            uint64_t nn1 = __ballot(v1 != 0.f);
            if (lane == 0) {
                wbuf[r]        = make_ulonglong2(ss0, ss1);
                wbuf[FDIM + r] = make_ulonglong2(nn0, nn1);
            }
        }
    }
    #pragma unroll 4
    for (int k = 0; k < 32; ++k) {
        int lr = (wv << 5) + k;
        int64_t r = row0 + lr;
        bool ok = r < (int64_t)nrows;          // uniform across the wave
        const float* xr = x + r * FDIM;
        float v0 = ok ? xr[lane] : 0.f;
        float v1 = (ok && lane < FDIM - 64) ? xr[64 + lane] : 0.f;
        uint64_t ss0 = __ballot(v0 < 0.f);
        uint64_t nn0 = __ballot(v0 != 0.f);
        uint64_t ss1 = __ballot(v1 < 0.f);
        uint64_t nn1 = __ballot(v1 != 0.f);
        if (lane == 0 && ok) {
            xbuf[2 * r]     = make_ulonglong2(ss0, ss1);
            xbuf[2 * r + 1] = make_ulonglong2(nn0, nn1);
        }
    }
}

// ================= K2: compute from bitmasks (v15 chain, verbatim) =================
__global__ __launch_bounds__(TPB) void bnn_compute(
    const ulonglong2* __restrict__ wbuf,
    const ulonglong2* __restrict__ xbuf,
    const float* __restrict__ gn1_w, const float* __restrict__ gn1_b,
    const float* __restrict__ gn2_w, const float* __restrict__ gn2_b,
    const float* __restrict__ lin_w, const float* __restrict__ lin_b,
    const float* __restrict__ gn3_w, const float* __restrict__ gn3_b,
    float* __restrict__ out, int nrows)
{
    #pragma clang fp contract(off)
    __shared__ ulonglong2 s_ws[FDIM];
    __shared__ ulonglong2 s_wn[FDIM];
    __shared__ float2 s_g1[FDIM];
    __shared__ float2 s_g2[FDIM];
    __shared__ int8_t s_sl0[128];
    __shared__ int8_t s_sl1[128];
    __shared__ int s_flags;
    __shared__ uint32_t s_h[32 * TPB];

    const int t = threadIdx.x;
    const int64_t row = (int64_t)blockIdx.x * TPB + t;
    const bool rowOK = row < (int64_t)nrows;

    if (t == 0) s_flags = 0;
    __syncthreads();

    if (t < FDIM) {
        ulonglong2 wsv = wbuf[t];
        ulonglong2 wnv = wbuf[FDIM + t];
        s_ws[t] = wsv;
        s_wn[t] = wnv;
        if (__popcll(wnv.x) + __popcll(wnv.y) != FDIM) atomicOr(&s_flags, 1);
        float g1wv = gn1_w[t], g1bv = gn1_b[t];
        float g2wv = gn2_w[t], g2bv = gn2_b[t];
        s_g1[t] = make_float2(g1wv, g1bv);
        s_g2[t] = make_float2(g2wv, g2bv);
        if (g1wv != 1.f || g1bv != 0.f) atomicOr(&s_flags, 2);
        if (g2wv != 1.f || g2bv != 0.f) atomicOr(&s_flags, 4);
        float l0 = lin_w[t], l1 = lin_w[FDIM + t];
        s_sl0[t] = (int8_t)((l0 > 0.f) - (l0 < 0.f));
        s_sl1[t] = (int8_t)((l1 > 0.f) - (l1 < 0.f));
    }

    // own row's masks: coalesced 2 x b128 from global (L2/L3-hot, 8 MB total)
    ulonglong2 xs = make_ulonglong2(0, 0), xn = make_ulonglong2(0, 0);
    if (rowOK) {
        xs = xbuf[2 * row];
        xn = xbuf[2 * row + 1];
    }
    const int Kx = __popcll(xn.x) + __popcll(xn.y);
    __syncthreads();
    const int flags = s_flags;

    // ---- compute h ONCE, packed bytes into own s_h column; integer row sum ----
    int sum = 0;
    if (!(flags & 1)) {
        for (int g = 0; g < 32; ++g) {
            uint32_t pack = 0;
            #pragma unroll
            for (int j = 0; j < 4; ++j) {
                int cc = 4 * g + j;
                if (cc < FDIM) {
                    ulonglong2 w = s_ws[cc];
                    int pc = __popcll((xs.x ^ w.x) & xn.x) + __popcll((xs.y ^ w.y) & xn.y);
                    int h = Kx - 2 * pc;
                    sum += h;
                    pack |= (uint32_t)(h & 255) << (8 * j);
                }
            }
            s_h[g * TPB + t] = pack;
        }
    } else {
        for (int g = 0; g < 32; ++g) {
            uint32_t pack = 0;
            #pragma unroll
            for (int j = 0; j < 4; ++j) {
                int cc = 4 * g + j;
                if (cc < FDIM) {
                    ulonglong2 w = s_ws[cc];
                    ulonglong2 wn = s_wn[cc];
                    uint64_t m0 = xn.x & wn.x, m1 = xn.y & wn.y;
                    int pm = __popcll(m0) + __popcll(m1);
                    int pc = __popcll((xs.x ^ w.x) & m0) + __popcll((xs.y ^ w.y) & m1);
                    int h = pm - 2 * pc;
                    sum += h;
                    pack |= (uint32_t)(h & 255) << (8 * j);
                }
            }
            s_h[g * TPB + t] = pack;
        }
    }

    auto hdw = [&](int g) -> uint32_t { return s_h[g * TPB + t]; };
    auto hget = [&](int i) -> int { return BEXT(hdw(i >> 2), i & 3); };

    // ---- GN1 var in f32: np pairwise tree, dword-batched (PROVEN v15) ----
    const float mu1f = (float)sum / 126.0f;
    float var1f;
    {
        uint32_t u0 = hdw(0), u1 = hdw(1);
        float e;
        e = (float)BEXT(u0,0) - mu1f; float q0 = e*e;
        e = (float)BEXT(u0,1) - mu1f; float q1 = e*e;
        e = (float)BEXT(u0,2) - mu1f; float q2 = e*e;
        e = (float)BEXT(u0,3) - mu1f; float q3 = e*e;
        e = (float)BEXT(u1,0) - mu1f; float q4 = e*e;
        e = (float)BEXT(u1,1) - mu1f; float q5 = e*e;
        e = (float)BEXT(u1,2) - mu1f; float q6 = e*e;
        e = (float)BEXT(u1,3) - mu1f; float q7 = e*e;
        for (int k = 1; k < 15; ++k) {
            uint32_t a0 = hdw(2*k), a1 = hdw(2*k + 1);
            e = (float)BEXT(a0,0) - mu1f; q0 += e*e;
            e = (float)BEXT(a0,1) - mu1f; q1 += e*e;
            e = (float)BEXT(a0,2) - mu1f; q2 += e*e;
            e = (float)BEXT(a0,3) - mu1f; q3 += e*e;
            e = (float)BEXT(a1,0) - mu1f; q4 += e*e;
            e = (float)BEXT(a1,1) - mu1f; q5 += e*e;
            e = (float)BEXT(a1,2) - mu1f; q6 += e*e;
            e = (float)BEXT(a1,3) - mu1f; q7 += e*e;
        }
        float res = ((q0 + q1) + (q2 + q3)) + ((q4 + q5) + (q6 + q7));
        uint32_t u30 = hdw(30), u31 = hdw(31);
        e = (float)BEXT(u30,0) - mu1f; res += e*e;
        e = (float)BEXT(u30,1) - mu1f; res += e*e;
        e = (float)BEXT(u30,2) - mu1f; res += e*e;
        e = (float)BEXT(u30,3) - mu1f; res += e*e;
        e = (float)BEXT(u31,0) - mu1f; res += e*e;
        e = (float)BEXT(u31,1) - mu1f; res += e*e;
        var1f = res / 126.0f;
    }
    const double r1 = 1.0 / sqrt((double)var1f + 1e-5);   // f64 literal promotes

    auto c1ofh = [&](int hv) -> double {
        #pragma clang fp contract(off)
        float e32 = (float)hv - mu1f;
        double y = (double)e32 * r1;
        return fmin(fmax(y, -1.0), 1.0);
    };

    int ip0 = 0, ip1 = 0;
    if (!(flags & 6)) {
        // ---- mu2: f64 np pairwise tree, dword-batched (PROVEN v15) ----
        double mu2;
        {
            uint32_t u0 = hdw(0), u1 = hdw(1);
            double q0 = c1ofh(BEXT(u0,0)), q1 = c1ofh(BEXT(u0,1));
            double q2 = c1ofh(BEXT(u0,2)), q3 = c1ofh(BEXT(u0,3));
            double q4 = c1ofh(BEXT(u1,0)), q5 = c1ofh(BEXT(u1,1));
            double q6 = c1ofh(BEXT(u1,2)), q7 = c1ofh(BEXT(u1,3));
            for (int k = 1; k < 15; ++k) {
                uint32_t a0 = hdw(2*k), a1 = hdw(2*k + 1);
                q0 += c1ofh(BEXT(a0,0)); q1 += c1ofh(BEXT(a0,1));
                q2 += c1ofh(BEXT(a0,2)); q3 += c1ofh(BEXT(a0,3));
                q4 += c1ofh(BEXT(a1,0)); q5 += c1ofh(BEXT(a1,1));
                q6 += c1ofh(BEXT(a1,2)); q7 += c1ofh(BEXT(a1,3));
            }
            double res = ((q0 + q1) + (q2 + q3)) + ((q4 + q5) + (q6 + q7));
            uint32_t u30 = hdw(30), u31 = hdw(31);
            res += c1ofh(BEXT(u30,0)); res += c1ofh(BEXT(u30,1));
            res += c1ofh(BEXT(u30,2)); res += c1ofh(BEXT(u30,3));
            res += c1ofh(BEXT(u31,0)); res += c1ofh(BEXT(u31,1));
            mu2 = res / 126.0;
        }

        // ---- integer thresholds via monotone binary search (PROVEN v15) ----
        const double c127 = c1ofh(127);
        int lo1 = -127, hi1 = 127, lo2 = -127, hi2 = 127;
        #pragma unroll
        for (int it = 0; it < 8; ++it) {
            int m1 = (lo1 + hi1) >> 1;
            bool ge = (c1ofh(m1) >= mu2);
            hi1 = ge ? m1 : hi1;  lo1 = ge ? lo1 : m1 + 1;
            int m2 = (lo2 + hi2) >> 1;
            bool gt = (c1ofh(m2) > mu2);
            hi2 = gt ? m2 : hi2;  lo2 = gt ? lo2 : m2 + 1;
        }
        const int vge = (c127 >= mu2) ? lo1 : 128;
        const int vgt = (c127 >  mu2) ? lo2 : 128;

        for (int g = 0; g < 31; ++g) {
            uint32_t u = hdw(g);
            #pragma unroll
            for (int j = 0; j < 4; ++j) {
                int c = 4 * g + j;
                int hv = BEXT(u, j);
                int hb = (hv >= vgt) - (hv < vge);
                ip0 += hb * (int)s_sl0[c];
                ip1 += hb * (int)s_sl1[c];
            }
        }
        {
            uint32_t u = hdw(31);
            #pragma unroll
            for (int j = 0; j < 2; ++j) {
                int hv = BEXT(u, j);
                int hb = (hv >= vgt) - (hv < vge);
                ip0 += hb * (int)s_sl0[124 + j];
                ip1 += hb * (int)s_sl1[124 + j];
            }
        }
    } else {
        // ---- general path (not taken for this data): v14-verbatim np mirror ----
        auto c1f = [&](int i) -> double {
            #pragma clang fp contract(off)
            float e32 = (float)hget(i) - mu1f;
            float2 g = s_g1[i];
            double y = (((double)e32 * r1) * (double)g.x) + (double)g.y;
            return fmin(fmax(y, -1.0), 1.0);
        };
        const double mu2 = pw126d(c1f) / 126.0;
        const double var2 = pw126d([&](int i) -> double {
            #pragma clang fp contract(off)
            double e2 = c1f(i) - mu2;
            return e2 * e2;
        }) / 126.0;
        const double r2 = 1.0 / sqrt(var2 + 1e-5);
        for (int c = 0; c < FDIM; ++c) {
            double e2 = c1f(c) - mu2;
            float2 g2 = s_g2[c];
            double z = ((e2 * r2) * (double)g2.x) + (double)g2.y;
            int hb = (z > 0.0) - (z < 0.0);
            ip0 += hb * (int)s_sl0[c];
            ip1 += hb * (int)s_sl1[c];
        }
    }

    // ---- BNNLinear + GN3 in f64 (PROVEN) ----
    if (rowOK) {
        double o0 = (double)ip0 + (double)lin_b[0];
        double o1 = (double)ip1 + (double)lin_b[1];
        double mu = (o0 + o1) / 2.0;
        double d0 = o0 - mu, d1 = o1 - mu;
        double var = ((d0 * d0) + (d1 * d1)) / 2.0;
        double r3 = 1.0 / sqrt(var + 1e-5);
        double q0 = ((d0 * r3) * (double)gn3_w[0]) + (double)gn3_b[0];
        double q1 = ((d1 * r3) * (double)gn3_w[1]) + (double)gn3_b[1];
        reinterpret_cast<float2*>(out)[row] = make_float2((float)q0, (float)q1);
    }
}

// ================= Fallback: v15 single-kernel (proven), if ws too small =========
__global__ __launch_bounds__(TPB) void bnn_v15(
    const float* __restrict__ x,
    const float* __restrict__ conv_w,
    const float* __restrict__ gn1_w, const float* __restrict__ gn1_b,
    const float* __restrict__ gn2_w, const float* __restrict__ gn2_b,
    const float* __restrict__ lin_w, const float* __restrict__ lin_b,
    const float* __restrict__ gn3_w, const float* __restrict__ gn3_b,
    float* __restrict__ out, int nrows)
{
    #pragma clang fp contract(off)
    __shared__ ulonglong2 s_ws[FDIM];
    __shared__ ulonglong2 s_wn[FDIM];
    __shared__ float2 s_g1[FDIM];
    __shared__ float2 s_g2[FDIM];
    __shared__ int8_t s_sl0[128];
    __shared__ int8_t s_sl1[128];
    __shared__ int s_flags;
    __shared__ __align__(16) uint8_t s_pool[TPB * 128];

    ulonglong2* s_xs = (ulonglong2*)s_pool;
    ulonglong2* s_xn = (ulonglong2*)(s_pool + 4096);
    uint32_t*   s_h  = (uint32_t*)s_pool;

    const int t = threadIdx.x;
    const int lane = t & 63;
    const int wv = t >> 6;
    const int64_t row0 = (int64_t)blockIdx.x * TPB;
    const int64_t row = row0 + t;
    const bool rowOK = row < (int64_t)nrows;

    if (t == 0) s_flags = 0;
    __syncthreads();

    for (int r = wv; r < FDIM; r += 4) {
        const float* wr = conv_w + (size_t)r * FDIM;
        float v0 = wr[lane];
        float v1 = (lane < FDIM - 64) ? wr[64 + lane] : 0.f;
        uint64_t ss0 = __ballot(v0 < 0.f);
        uint64_t nn0 = __ballot(v0 != 0.f);
        uint64_t ss1 = __ballot(v1 < 0.f);
        uint64_t nn1 = __ballot(v1 != 0.f);
        if (lane == 0) {
            s_ws[r] = make_ulonglong2(ss0, ss1);
            s_wn[r] = make_ulonglong2(nn0, nn1);
            if (__popcll(nn0) + __popcll(nn1) != FDIM) atomicOr(&s_flags, 1);
        }
    }
    #pragma unroll 4
    for (int k = 0; k < 64; ++k) {
        int lr = (wv << 6) + k;
        int64_t r = row0 + lr;
        bool ok = r < (int64_t)nrows;
        const float* xr = x + r * FDIM;
        float v0 = ok ? xr[lane] : 0.f;
        float v1 = (ok && lane < FDIM - 64) ? xr[64 + lane] : 0.f;
        uint64_t ss0 = __ballot(v0 < 0.f);
        uint64_t nn0 = __ballot(v0 != 0.f);
        uint64_t ss1 = __ballot(v1 < 0.f);
        uint64_t nn1 = __ballot(v1 != 0.f);
        if (lane == 0) {
            s_xs[lr] = make_ulonglong2(ss0, ss1);
            s_xn[lr] = make_ulonglong2(nn0, nn1);
        }
    }
    if (t < FDIM) {
        float g1wv = gn1_w[t], g1bv = gn1_b[t];
        float g2wv = gn2_w[t], g2bv = gn2_b[t];
        s_g1[t] = make_float2(g1wv, g1bv);
        s_g2[t] = make_float2(g2wv, g2bv);
        if (g1wv != 1.f || g1bv != 0.f) atomicOr(&s_flags, 2);
        if (g2wv != 1.f || g2bv != 0.f) atomicOr(&s_flags, 4);
        float l0 = lin_w[t], l1 = lin_w[FDIM + t];
        s_sl0[t] = (int8_t)((l0 > 0.f) - (l0 < 0.f));
        s_sl1[t] = (int8_t)((l1 > 0.f) - (l1 < 0.f));
    }
    __syncthreads();
    const int flags = s_flags;

    const ulonglong2 xs = s_xs[t];
    const ulonglong2 xn = s_xn[t];
    const int Kx = __popcll(xn.x) + __popcll(xn.y);
    __syncthreads();

    int sum = 0;
    if (!(flags & 1)) {
        for (int g = 0; g < 32; ++g) {
            uint32_t pack = 0;
            #pragma unroll
            for (int j = 0; j < 4; ++j) {
                int cc = 4 * g + j;
                if (cc < FDIM) {
                    ulonglong2 w = s_ws[cc];
                    int pc = __popcll((xs.x ^ w.x) & xn.x) + __popcll((xs.y ^ w.y) & xn.y);
                    int h = Kx - 2 * pc;
                    sum += h;
                    pack |= (uint32_t)(h & 255) << (8 * j);
                }
            }
            s_h[g * TPB + t] = pack;
        }
    } else {
        for (int g = 0; g < 32; ++g) {
            uint32_t pack = 0;
            #pragma unroll
            for (int j = 0; j < 4; ++j) {
                int cc = 4 * g + j;
                if (cc < FDIM) {
                    ulonglong2 w = s_ws[cc];
                    ulonglong2 wn = s_wn[cc];
                    uint64_t m0 = xn.x & wn.x, m1 = xn.y & wn.y;
                    int pm = __popcll(m0) + __popcll(m1);
                    int pc = __popcll((xs.x ^ w.x) & m0) + __popcll((xs.y ^ w.y) & m1);
                    int h = pm - 2 * pc;
                    sum += h;
                    pack |= (uint32_t)(h & 255) << (8 * j);
                }
            }
            s_h[g * TPB + t] = pack;
        }
    }

    auto hdw = [&](int g) -> uint32_t { return s_h[g * TPB + t]; };
    auto hget = [&](int i) -> int { return BEXT(hdw(i >> 2), i & 3); };

    const float mu1f = (float)sum / 126.0f;
    float var1f;
    {
        uint32_t u0 = hdw(0), u1 = hdw(1);
        float e;
        e = (float)BEXT(u0,0) - mu1f; float q0 = e*e;
        e = (float)BEXT(u0,1) - mu1f; float q1 = e*e;
        e = (float)BEXT(u0,2) - mu1f; float q2 = e*e;
        e = (float)BEXT(u0,3) - mu1f; float q3 = e*e;
        e = (float)BEXT(u1,0) - mu1f; float q4 = e*e;
        e = (float)BEXT(u1,1) - mu1f; float q5 = e*e;
        e = (float)BEXT(u1,2) - mu1f; float q6 = e*e;
        e = (float)BEXT(u1,3) - mu1f; float q7 = e*e;
        for (int k = 1; k < 15; ++k) {
            uint32_t a0 = hdw(2*k), a1 = hdw(2*k + 1);
            e = (float)BEXT(a0,0) - mu1f; q0 += e*e;
            e = (float)BEXT(a0,1) - mu1f; q1 += e*e;
            e = (float)BEXT(a0,2) - mu1f; q2 += e*e;
            e = (float)BEXT(a0,3) - mu1f; q3 += e*e;
            e = (float)BEXT(a1,0) - mu1f; q4 += e*e;
            e = (float)BEXT(a1,1) - mu1f; q5 += e*e;
            e = (float)BEXT(a1,2) - mu1f; q6 += e*e;
            e = (float)BEXT(a1,3) - mu1f; q7 += e*e;
        }
        float res = ((q0 + q1) + (q2 + q3)) + ((q4 + q5) + (q6 + q7));
        uint32_t u30 = hdw(30), u31 = hdw(31);
        e = (float)BEXT(u30,0) - mu1f; res += e*e;
        e = (float)BEXT(u30,1) - mu1f; res += e*e;
        e = (float)BEXT(u30,2) - mu1f; res += e*e;
        e = (float)BEXT(u30,3) - mu1f; res += e*e;
        e = (float)BEXT(u31,0) - mu1f; res += e*e;
        e = (float)BEXT(u31,1) - mu1f; res += e*e;
        var1f = res / 126.0f;
    }
    const double r1 = 1.0 / sqrt((double)var1f + 1e-5);

    auto c1ofh = [&](int hv) -> double {
        #pragma clang fp contract(off)
        float e32 = (float)hv - mu1f;
        double y = (double)e32 * r1;
        return fmin(fmax(y, -1.0), 1.0);
    };

    int ip0 = 0, ip1 = 0;
    if (!(flags & 6)) {
        double mu2;
        {
            uint32_t u0 = hdw(0), u1 = hdw(1);
            double q0 = c1ofh(BEXT(u0,0)), q1 = c1ofh(BEXT(u0,1));
            double q2 = c1ofh(BEXT(u0,2)), q3 = c1ofh(BEXT(u0,3));
            double q4 = c1ofh(BEXT(u1,0)), q5 = c1ofh(BEXT(u1,1));
            double q6 = c1ofh(BEXT(u1,2)), q7 = c1ofh(BEXT(u1,3));
            for (int k = 1; k < 15; ++k) {
                uint32_t a0 = hdw(2*k), a1 = hdw(2*k + 1);
                q0 += c1ofh(BEXT(a0,0)); q1 += c1ofh(BEXT(a0,1));
                q2 += c1ofh(BEXT(a0,2)); q3 += c1ofh(BEXT(a0,3));
                q4 += c1ofh(BEXT(a1,0)); q5 += c1ofh(BEXT(a1,1));
                q6 += c1ofh(BEXT(a1,2)); q7 += c1ofh(BEXT(a1,3));
            }
            double res = ((q0 + q1) + (q2 + q3)) + ((q4 + q5) + (q6 + q7));
            uint32_t u30 = hdw(30), u31 = hdw(31);
            res += c1ofh(BEXT(u30,0)); res += c1ofh(BEXT(u30,1));
            res += c1ofh(BEXT(u30,2)); res += c1ofh(BEXT(u30,3));
            res += c1ofh(BEXT(u31,0)); res += c1ofh(BEXT(u31,1));
            mu2 = res / 126.0;
        }
        const double c127 = c1ofh(127);
        int lo1 = -127, hi1 = 127, lo2 = -127, hi2 = 127;
        #pragma unroll
        for (int it = 0; it < 8; ++it) {
            int m1 = (lo1 + hi1) >> 1;
            bool ge = (c1ofh(m1) >= mu2);
            hi1 = ge ? m1 : hi1;  lo1 = ge ? lo1 : m1 + 1;
            int m2 = (lo2 + hi2) >> 1;
            bool gt = (c1ofh(m2) > mu2);
            hi2 = gt ? m2 : hi2;  lo2 = gt ? lo2 : m2 + 1;
        }
        const int vge = (c127 >= mu2) ? lo1 : 128;
        const int vgt = (c127 >  mu2) ? lo2 : 128;

        for (int g = 0; g < 31; ++g) {
            uint32_t u = hdw(g);
            #pragma unroll
            for (int j = 0; j < 4; ++j) {
                int c = 4 * g + j;
                int hv = BEXT(u, j);
                int hb = (hv >= vgt) - (hv < vge);
                ip0 += hb * (int)s_sl0[c];
                ip1 += hb * (int)s_sl1[c];
            }
        }
        {
            uint32_t u = hdw(31);
            #pragma unroll
            for (int j = 0; j < 2; ++j) {
                int hv = BEXT(u, j);
                int hb = (hv >= vgt) - (hv < vge);
                ip0 += hb * (int)s_sl0[124 + j];
                ip1 += hb * (int)s_sl1[124 + j];
            }
        }
    } else {
        auto c1f = [&](int i) -> double {
            #pragma clang fp contract(off)
            float e32 = (float)hget(i) - mu1f;
            float2 g = s_g1[i];
            double y = (((double)e32 * r1) * (double)g.x) + (double)g.y;
            return fmin(fmax(y, -1.0), 1.0);
        };
        const double mu2 = pw126d(c1f) / 126.0;
        const double var2 = pw126d([&](int i) -> double {
            #pragma clang fp contract(off)
            double e2 = c1f(i) - mu2;
            return e2 * e2;
        }) / 126.0;
        const double r2 = 1.0 / sqrt(var2 + 1e-5);
        for (int c = 0; c < FDIM; ++c) {
            double e2 = c1f(c) - mu2;
            float2 g2 = s_g2[c];
            double z = ((e2 * r2) * (double)g2.x) + (double)g2.y;
            int hb = (z > 0.0) - (z < 0.0);
            ip0 += hb * (int)s_sl0[c];
            ip1 += hb * (int)s_sl1[c];
        }
    }

    if (rowOK) {
        double o0 = (double)ip0 + (double)lin_b[0];
        double o1 = (double)ip1 + (double)lin_b[1];
        double mu = (o0 + o1) / 2.0;
        double d0 = o0 - mu, d1 = o1 - mu;
        double var = ((d0 * d0) + (d1 * d1)) / 2.0;
        double r3 = 1.0 / sqrt(var + 1e-5);
        double q0 = ((d0 * r3) * (double)gn3_w[0]) + (double)gn3_b[0];
        double q1 = ((d1 * r3) * (double)gn3_w[1]) + (double)gn3_b[1];
        reinterpret_cast<float2*>(out)[row] = make_float2((float)q0, (float)q1);
    }
}

extern "C" void kernel_launch(void* const* d_in, const int* in_sizes, int n_in,
                              void* d_out, int out_size, void* d_ws, size_t ws_size,
                              hipStream_t stream) {
    const float* x      = (const float*)d_in[0];
    const float* conv_w = (const float*)d_in[1];
    const float* gn1_w  = (const float*)d_in[2];
    const float* gn1_b  = (const float*)d_in[3];
    const float* gn2_w  = (const float*)d_in[4];
    const float* gn2_b  = (const float*)d_in[5];
    const float* lin_w  = (const float*)d_in[6];
    const float* lin_b  = (const float*)d_in[7];
    const float* gn3_w  = (const float*)d_in[8];
    const float* gn3_b  = (const float*)d_in[9];
    float* out = (float*)d_out;

    int nrows = in_sizes[0] / FDIM;
    size_t need = 4096 + (size_t)nrows * 32;

    if (d_ws != nullptr && ws_size >= need) {
        ulonglong2* wbuf = (ulonglong2*)d_ws;
        ulonglong2* xbuf = (ulonglong2*)((char*)d_ws + 4096);
        int nb1 = (nrows + 127) / 128;
        bnn_pack<<<nb1, TPB, 0, stream>>>(x, conv_w, wbuf, xbuf, nrows);
        int nb2 = (nrows + TPB - 1) / TPB;
        bnn_compute<<<nb2, TPB, 0, stream>>>(wbuf, xbuf, gn1_w, gn1_b, gn2_w, gn2_b,
                                             lin_w, lin_b, gn3_w, gn3_b, out, nrows);
    } else {
        int nblocks = (nrows + TPB - 1) / TPB;
        bnn_v15<<<nblocks, TPB, 0, stream>>>(x, conv_w, gn1_w, gn1_b, gn2_w, gn2_b,
                                             lin_w, lin_b, gn3_w, gn3_b, out, nrows);
    }
}